// Round 1
// baseline (1536.182 us; speedup 1.0000x reference)
//
#include <hip/hip_runtime.h>
#include <hip/hip_bf16.h>
#include <cstddef>

// Problem constants
#define B_    8
#define N_    1024
#define EMB_  768
#define HEADS_ 12
#define HDIM_ 64
#define M_TOK (B_ * N_)            // 8192 tokens
#define QKVF  (3 * EMB_)           // 2304
#define OUT_ELEMS ((size_t)M_TOK * EMB_)              // 6,291,456
#define ATTN_ELEMS ((size_t)B_ * HEADS_ * N_ * N_)    // 100,663,296

// ---------------------------------------------------------------------------
// Generic tiled fp32 GEMM: C[M,N] = A[M,K] * B[N,K]^T + bias[N]
// A row-major stride lda, B row-major stride ldb (reduction along contiguous
// dim of both), C row-major stride ldc. Tile 64x64, BK=16, 256 threads, each
// thread computes a 4x4 micro-tile. LDS stored k-major so inner-loop reads
// are contiguous float4 (ds_read_b128).
// ---------------------------------------------------------------------------
__global__ __launch_bounds__(256) void gemm_bt(
    const float* __restrict__ A, int lda,
    const float* __restrict__ B, int ldb,
    const float* __restrict__ bias,
    float* __restrict__ C, int ldc,
    int K)
{
    __shared__ float As[16][64];   // [k][row]
    __shared__ float Bs[16][64];   // [k][col]

    const int t  = threadIdx.x;
    const int tx = t & 15;         // col group 0..15
    const int ty = t >> 4;         // row group 0..15
    const int row0 = blockIdx.y * 64;
    const int col0 = blockIdx.x * 64;

    // staging map: thread loads float4 along K; lrow 0..63, lk in {0,4,8,12}
    const int lrow = t >> 2;
    const int lk   = (t & 3) << 2;

    float acc[4][4] = {};

    for (int k0 = 0; k0 < K; k0 += 16) {
        const float4 av = *reinterpret_cast<const float4*>(
            &A[(size_t)(row0 + lrow) * lda + k0 + lk]);
        const float4 bv = *reinterpret_cast<const float4*>(
            &B[(size_t)(col0 + lrow) * ldb + k0 + lk]);
        __syncthreads();
        As[lk + 0][lrow] = av.x; As[lk + 1][lrow] = av.y;
        As[lk + 2][lrow] = av.z; As[lk + 3][lrow] = av.w;
        Bs[lk + 0][lrow] = bv.x; Bs[lk + 1][lrow] = bv.y;
        Bs[lk + 2][lrow] = bv.z; Bs[lk + 3][lrow] = bv.w;
        __syncthreads();
#pragma unroll
        for (int kk = 0; kk < 16; ++kk) {
            const float4 a4 = *reinterpret_cast<const float4*>(&As[kk][ty << 2]);
            const float4 b4 = *reinterpret_cast<const float4*>(&Bs[kk][tx << 2]);
            const float ar[4] = {a4.x, a4.y, a4.z, a4.w};
            const float br[4] = {b4.x, b4.y, b4.z, b4.w};
#pragma unroll
            for (int i = 0; i < 4; ++i)
#pragma unroll
                for (int j = 0; j < 4; ++j)
                    acc[i][j] += ar[i] * br[j];
        }
    }

    const int c = col0 + (tx << 2);
    const float4 bb = bias ? *reinterpret_cast<const float4*>(&bias[c])
                           : make_float4(0.f, 0.f, 0.f, 0.f);
#pragma unroll
    for (int i = 0; i < 4; ++i) {
        const int r = row0 + (ty << 2) + i;
        float4 o;
        o.x = acc[i][0] + bb.x;
        o.y = acc[i][1] + bb.y;
        o.z = acc[i][2] + bb.z;
        o.w = acc[i][3] + bb.w;
        *reinterpret_cast<float4*>(&C[(size_t)r * ldc + c]) = o;
    }
}

// ---------------------------------------------------------------------------
// Scores: S[b,h,n,m] = (1/8) * sum_d Q[b,n,h,d] * K[b,m,h,d]
// Q,K live in qkv[M_TOK, 2304] (Q offset 0, K offset 768).
// Block = 64x64 tile of S for one (b,h); LDS stores d-major for float4 reads.
// ---------------------------------------------------------------------------
__global__ __launch_bounds__(256) void scores_kernel(
    const float* __restrict__ qkv, float* __restrict__ attn)
{
    __shared__ float Qs[64][64];   // [d][n]
    __shared__ float Ks[64][64];   // [d][m]

    const int bh = blockIdx.z;               // 0..95
    const int b  = bh / HEADS_;
    const int h  = bh % HEADS_;
    const int n0 = blockIdx.y * 64;
    const int m0 = blockIdx.x * 64;
    const int t  = threadIdx.x;
    const int tx = t & 15, ty = t >> 4;

    const int qoff = h * HDIM_;
    const int koff = EMB_ + h * HDIM_;

#pragma unroll
    for (int cIt = 0; cIt < 4; ++cIt) {
        const int f   = t + cIt * 256;       // float4 index 0..1023
        const int row = f >> 4;              // 0..63
        const int d0  = (f & 15) << 2;       // 0..60
        const float4 q = *reinterpret_cast<const float4*>(
            &qkv[(size_t)(b * N_ + n0 + row) * QKVF + qoff + d0]);
        const float4 k = *reinterpret_cast<const float4*>(
            &qkv[(size_t)(b * N_ + m0 + row) * QKVF + koff + d0]);
        Qs[d0 + 0][row] = q.x; Qs[d0 + 1][row] = q.y;
        Qs[d0 + 2][row] = q.z; Qs[d0 + 3][row] = q.w;
        Ks[d0 + 0][row] = k.x; Ks[d0 + 1][row] = k.y;
        Ks[d0 + 2][row] = k.z; Ks[d0 + 3][row] = k.w;
    }
    __syncthreads();

    float acc[4][4] = {};
#pragma unroll 16
    for (int kk = 0; kk < 64; ++kk) {
        const float4 a4 = *reinterpret_cast<const float4*>(&Qs[kk][ty << 2]);
        const float4 b4 = *reinterpret_cast<const float4*>(&Ks[kk][tx << 2]);
        const float ar[4] = {a4.x, a4.y, a4.z, a4.w};
        const float br[4] = {b4.x, b4.y, b4.z, b4.w};
#pragma unroll
        for (int i = 0; i < 4; ++i)
#pragma unroll
            for (int j = 0; j < 4; ++j)
                acc[i][j] += ar[i] * br[j];
    }

    const float scale = 0.125f;  // 1/sqrt(64)
#pragma unroll
    for (int i = 0; i < 4; ++i) {
        const size_t base = (((size_t)bh * N_) + n0 + (ty << 2) + i) * N_ + m0 + (tx << 2);
        float4 o;
        o.x = acc[i][0] * scale;
        o.y = acc[i][1] * scale;
        o.z = acc[i][2] * scale;
        o.w = acc[i][3] * scale;
        *reinterpret_cast<float4*>(&attn[base]) = o;
    }
}

// ---------------------------------------------------------------------------
// Row softmax in-place over 1024 elements. One 256-thread block per row.
// ---------------------------------------------------------------------------
__global__ __launch_bounds__(256) void softmax_kernel(float* __restrict__ attn)
{
    const size_t row = blockIdx.x;
    float* p = attn + row * N_;
    const int t = threadIdx.x;

    float4 v = *reinterpret_cast<float4*>(&p[t << 2]);

    float m = fmaxf(fmaxf(v.x, v.y), fmaxf(v.z, v.w));
#pragma unroll
    for (int off = 32; off > 0; off >>= 1)
        m = fmaxf(m, __shfl_xor(m, off));

    __shared__ float redm[4];
    __shared__ float reds[4];
    const int wid = t >> 6, lane = t & 63;
    if (lane == 0) redm[wid] = m;
    __syncthreads();
    m = fmaxf(fmaxf(redm[0], redm[1]), fmaxf(redm[2], redm[3]));

    const float e0 = expf(v.x - m);
    const float e1 = expf(v.y - m);
    const float e2 = expf(v.z - m);
    const float e3 = expf(v.w - m);

    float s = e0 + e1 + e2 + e3;
#pragma unroll
    for (int off = 32; off > 0; off >>= 1)
        s += __shfl_xor(s, off);
    if (lane == 0) reds[wid] = s;
    __syncthreads();
    s = reds[0] + reds[1] + reds[2] + reds[3];

    const float inv = 1.0f / s;
    float4 o; o.x = e0 * inv; o.y = e1 * inv; o.z = e2 * inv; o.w = e3 * inv;
    *reinterpret_cast<float4*>(&p[t << 2]) = o;
}

// ---------------------------------------------------------------------------
// attn @ V: O[b,n, h*64+d] = sum_m P[b,h,n,m] * V[b,m,h,d]
// Block: 64 query rows x full 64-dim head for one (b,h); loop m in 64-chunks.
// ---------------------------------------------------------------------------
__global__ __launch_bounds__(256) void attnv_kernel(
    const float* __restrict__ attn, const float* __restrict__ qkv,
    float* __restrict__ O)
{
    __shared__ float Ps[64][64];   // [m][n]
    __shared__ float Vs[64][64];   // [m][d]

    const int bh = blockIdx.y;
    const int b  = bh / HEADS_;
    const int h  = bh % HEADS_;
    const int n0 = blockIdx.x * 64;
    const int t  = threadIdx.x;
    const int tx = t & 15, ty = t >> 4;
    const int voff = 2 * EMB_ + h * HDIM_;

    float acc[4][4] = {};

    for (int m0 = 0; m0 < N_; m0 += 64) {
        __syncthreads();
#pragma unroll
        for (int cIt = 0; cIt < 4; ++cIt) {
            const int f   = t + cIt * 256;
            const int row = f >> 4;           // 0..63
            const int c0  = (f & 15) << 2;    // 0..60
            const float4 pv = *reinterpret_cast<const float4*>(
                &attn[(((size_t)bh * N_) + n0 + row) * N_ + m0 + c0]);
            Ps[c0 + 0][row] = pv.x; Ps[c0 + 1][row] = pv.y;
            Ps[c0 + 2][row] = pv.z; Ps[c0 + 3][row] = pv.w;
            const float4 vv = *reinterpret_cast<const float4*>(
                &qkv[(size_t)(b * N_ + m0 + row) * QKVF + voff + c0]);
            *reinterpret_cast<float4*>(&Vs[row][c0]) = vv;
        }
        __syncthreads();
#pragma unroll 16
        for (int kk = 0; kk < 64; ++kk) {
            const float4 a4 = *reinterpret_cast<const float4*>(&Ps[kk][ty << 2]);
            const float4 b4 = *reinterpret_cast<const float4*>(&Vs[kk][tx << 2]);
            const float ar[4] = {a4.x, a4.y, a4.z, a4.w};
            const float br[4] = {b4.x, b4.y, b4.z, b4.w};
#pragma unroll
            for (int i = 0; i < 4; ++i)
#pragma unroll
                for (int j = 0; j < 4; ++j)
                    acc[i][j] += ar[i] * br[j];
        }
    }

#pragma unroll
    for (int i = 0; i < 4; ++i) {
        const int r = b * N_ + n0 + (ty << 2) + i;
        const int c = h * HDIM_ + (tx << 2);
        float4 o;
        o.x = acc[i][0]; o.y = acc[i][1]; o.z = acc[i][2]; o.w = acc[i][3];
        *reinterpret_cast<float4*>(&O[(size_t)r * EMB_ + c]) = o;
    }
}

// ---------------------------------------------------------------------------
extern "C" void kernel_launch(void* const* d_in, const int* in_sizes, int n_in,
                              void* d_out, int out_size, void* d_ws, size_t ws_size,
                              hipStream_t stream)
{
    const float* x     = (const float*)d_in[0];
    const float* w_qkv = (const float*)d_in[1];
    const float* b_qkv = (const float*)d_in[2];
    const float* w_out = (const float*)d_in[3];
    const float* b_out = (const float*)d_in[4];

    float* out  = (float*)d_out;
    float* attn = out + OUT_ELEMS;

    float* qkv = (float*)d_ws;                       // [8192, 2304]
    float* O   = qkv + (size_t)M_TOK * QKVF;         // [8192, 768]

    const dim3 blk(256);

    // 1. QKV projection: qkv = x @ w_qkv^T + b_qkv
    gemm_bt<<<dim3(QKVF / 64, M_TOK / 64), blk, 0, stream>>>(
        x, EMB_, w_qkv, EMB_, b_qkv, qkv, QKVF, EMB_);

    // 2. scores -> attn region (raw scaled logits)
    scores_kernel<<<dim3(N_ / 64, N_ / 64, B_ * HEADS_), blk, 0, stream>>>(qkv, attn);

    // 3. softmax in-place
    softmax_kernel<<<dim3(B_ * HEADS_ * N_), blk, 0, stream>>>(attn);

    // 4. attn @ V -> O
    attnv_kernel<<<dim3(N_ / 64, B_ * HEADS_), blk, 0, stream>>>(attn, qkv, O);

    // 5. output projection: out = O @ w_out^T + b_out
    gemm_bt<<<dim3(EMB_ / 64, M_TOK / 64), blk, 0, stream>>>(
        O, EMB_, w_out, EMB_, b_out, out, EMB_, EMB_);
}

// Round 2
// 835.143 us; speedup vs baseline: 1.8394x; 1.8394x over previous
//
#include <hip/hip_runtime.h>
#include <hip/hip_bf16.h>
#include <cstddef>
#include <cstdint>

// Problem constants
#define B_     8
#define N_     1024
#define EMB_   768
#define HEADS_ 12
#define HDIM_  64
#define M_TOK  (B_ * N_)           // 8192
#define QKVF   (3 * EMB_)          // 2304
#define OUT_ELEMS  ((size_t)M_TOK * EMB_)            // 6,291,456
#define ATTN_ELEMS ((size_t)B_ * HEADS_ * N_ * N_)   // 100,663,296

using short8  = __attribute__((ext_vector_type(8))) short;   // 8 bf16 = 4 VGPRs
using floatx4 = __attribute__((ext_vector_type(4))) float;

__device__ __forceinline__ short f32_to_bf16(float f) {
    union { float f; unsigned u; } x; x.f = f;
    unsigned r = x.u + 0x7FFFu + ((x.u >> 16) & 1u);   // RNE
    return (short)(r >> 16);
}

// async global->LDS, 16B per lane; LDS dst = wave-uniform base + lane*16
__device__ __forceinline__ void gload_lds16(const void* g, void* l) {
    __builtin_amdgcn_global_load_lds(
        (const __attribute__((address_space(1))) void*)g,
        (__attribute__((address_space(3))) void*)l, 16, 0, 0);
}

__device__ __forceinline__ floatx4 mfma16(short8 a, short8 b, floatx4 c) {
    return __builtin_amdgcn_mfma_f32_16x16x32_bf16(a, b, c, 0, 0, 0);
}

// ---------------------------------------------------------------------------
// cast fp32 -> bf16, exact grid (n multiple of 1024)
// ---------------------------------------------------------------------------
__global__ __launch_bounds__(256) void cast_kernel(const float* __restrict__ in,
                                                   short* __restrict__ out) {
    const int i = (blockIdx.x * 256 + threadIdx.x) * 4;
    const float4 v = *reinterpret_cast<const float4*>(&in[i]);
    short s0 = f32_to_bf16(v.x), s1 = f32_to_bf16(v.y);
    short s2 = f32_to_bf16(v.z), s3 = f32_to_bf16(v.w);
    using short4v = __attribute__((ext_vector_type(4))) short;
    short4v s = {s0, s1, s2, s3};
    *reinterpret_cast<short4v*>(&out[i]) = s;
}

// ---------------------------------------------------------------------------
// bf16 MFMA GEMM: C[M,N] = A[M,K] * B[N,K]^T + bias
// 128x128 tile, BK=32, 4 waves (2x2), each wave 4x4 16x16 tiles.
// LDS [128 rows][4 chunks of 8 bf16], chunk swizzle pc = c ^ ((r>>1)&3).
// OUT_BF16: C is bf16 (short*) else fp32 (float*).
// ---------------------------------------------------------------------------
template <int OUT_BF16>
__global__ __launch_bounds__(256) void mfma_gemm_bt(
    const short* __restrict__ A, int lda,
    const short* __restrict__ Bm, int ldb,
    const float* __restrict__ bias,
    void* __restrict__ Cp, int ldc, int K)
{
    __shared__ short As[128 * 32];
    __shared__ short Bs[128 * 32];

    const int t = threadIdx.x, lane = t & 63, w = t >> 6;
    const int wy = w >> 1, wx = w & 1;
    const int row0 = blockIdx.y * 128;
    const int col0 = blockIdx.x * 128;
    const int m = lane & 15, kc = lane >> 4;
    const int sw = kc ^ ((m >> 1) & 3);

    floatx4 acc[4][4] = {};

    for (int k0 = 0; k0 < K; k0 += 32) {
        __syncthreads();
#pragma unroll
        for (int p = 0; p < 2; ++p) {
            const int ci = p * 256 + w * 64 + lane;
            const int r = ci >> 2, c = ci & 3;
            const int g = c ^ ((r >> 1) & 3);
            gload_lds16(&A[(size_t)(row0 + r) * lda + k0 + g * 8],
                        &As[(p * 256 + w * 64) * 8]);
            gload_lds16(&Bm[(size_t)(col0 + r) * ldb + k0 + g * 8],
                        &Bs[(p * 256 + w * 64) * 8]);
        }
        __syncthreads();

        short8 af[4], bf[4];
#pragma unroll
        for (int i = 0; i < 4; ++i)
            af[i] = *reinterpret_cast<const short8*>(
                &As[((wy * 64 + i * 16 + m) * 4 + sw) * 8]);
#pragma unroll
        for (int j = 0; j < 4; ++j)
            bf[j] = *reinterpret_cast<const short8*>(
                &Bs[((wx * 64 + j * 16 + m) * 4 + sw) * 8]);
#pragma unroll
        for (int i = 0; i < 4; ++i)
#pragma unroll
            for (int j = 0; j < 4; ++j)
                acc[i][j] = mfma16(af[i], bf[j], acc[i][j]);
    }

    const int rq = lane >> 4;
#pragma unroll
    for (int i = 0; i < 4; ++i) {
        const int rbase = row0 + wy * 64 + i * 16 + rq * 4;
#pragma unroll
        for (int j = 0; j < 4; ++j) {
            const int cc = col0 + wx * 64 + j * 16 + m;
            const float bb = bias[cc];
#pragma unroll
            for (int rg = 0; rg < 4; ++rg) {
                const float v = acc[i][j][rg] + bb;
                if (OUT_BF16)
                    ((short*)Cp)[(size_t)(rbase + rg) * ldc + cc] = f32_to_bf16(v);
                else
                    ((float*)Cp)[(size_t)(rbase + rg) * ldc + cc] = v;
            }
        }
    }
}

// ---------------------------------------------------------------------------
// Scores: S[bh,n,m] = 0.125 * sum_d Q[n,d]*K[m,d], bf16 in, fp32 out.
// 128x128 tile per block, K=64 staged once. LDS [128][8 chunks], pc = c^(r&7).
// ---------------------------------------------------------------------------
__global__ __launch_bounds__(256) void mfma_scores(
    const short* __restrict__ qkv, float* __restrict__ attn)
{
    __shared__ short Qs[128 * 64];
    __shared__ short Ks[128 * 64];

    const int t = threadIdx.x, lane = t & 63, w = t >> 6;
    const int wy = w >> 1, wx = w & 1;
    const int bh = blockIdx.z, b = bh / HEADS_, h = bh % HEADS_;
    const int n0 = blockIdx.y * 128, m0 = blockIdx.x * 128;
    const size_t qbase = (size_t)(b * N_) * QKVF + h * HDIM_;
    const size_t kbase = qbase + EMB_;

#pragma unroll
    for (int p = 0; p < 4; ++p) {
        const int ci = p * 256 + w * 64 + lane;
        const int r = ci >> 3, c = ci & 7;
        const int g = c ^ (r & 7);
        gload_lds16(&qkv[qbase + (size_t)(n0 + r) * QKVF + g * 8],
                    &Qs[(p * 256 + w * 64) * 8]);
        gload_lds16(&qkv[kbase + (size_t)(m0 + r) * QKVF + g * 8],
                    &Ks[(p * 256 + w * 64) * 8]);
    }
    __syncthreads();

    const int m = lane & 15, kc = lane >> 4;
    floatx4 acc[4][4] = {};
#pragma unroll
    for (int ks = 0; ks < 2; ++ks) {
        const int chunk = ks * 4 + kc;
        const int pcs = chunk ^ (m & 7);
        short8 af[4], bf[4];
#pragma unroll
        for (int i = 0; i < 4; ++i)
            af[i] = *reinterpret_cast<const short8*>(
                &Qs[((wy * 64 + i * 16 + m) * 8 + pcs) * 8]);
#pragma unroll
        for (int j = 0; j < 4; ++j)
            bf[j] = *reinterpret_cast<const short8*>(
                &Ks[((wx * 64 + j * 16 + m) * 8 + pcs) * 8]);
#pragma unroll
        for (int i = 0; i < 4; ++i)
#pragma unroll
            for (int j = 0; j < 4; ++j)
                acc[i][j] = mfma16(af[i], bf[j], acc[i][j]);
    }

    const int rq = lane >> 4;
#pragma unroll
    for (int i = 0; i < 4; ++i)
#pragma unroll
        for (int j = 0; j < 4; ++j)
#pragma unroll
            for (int rg = 0; rg < 4; ++rg) {
                const int row = n0 + wy * 64 + i * 16 + rq * 4 + rg;
                const int col = m0 + wx * 64 + j * 16 + m;
                attn[((size_t)bh * N_ + row) * N_ + col] = acc[i][j][rg] * 0.125f;
            }
}

// ---------------------------------------------------------------------------
// Row softmax in-place over 1024 fp32. One 256-thread block per row.
// ---------------------------------------------------------------------------
__global__ __launch_bounds__(256) void softmax_kernel(float* __restrict__ attn)
{
    const size_t row = blockIdx.x;
    float* p = attn + row * N_;
    const int t = threadIdx.x;

    float4 v = *reinterpret_cast<float4*>(&p[t << 2]);

    float mx = fmaxf(fmaxf(v.x, v.y), fmaxf(v.z, v.w));
#pragma unroll
    for (int off = 32; off > 0; off >>= 1)
        mx = fmaxf(mx, __shfl_xor(mx, off));

    __shared__ float redm[4];
    __shared__ float reds[4];
    const int wid = t >> 6, lane = t & 63;
    if (lane == 0) redm[wid] = mx;
    __syncthreads();
    mx = fmaxf(fmaxf(redm[0], redm[1]), fmaxf(redm[2], redm[3]));

    const float e0 = expf(v.x - mx);
    const float e1 = expf(v.y - mx);
    const float e2 = expf(v.z - mx);
    const float e3 = expf(v.w - mx);

    float s = e0 + e1 + e2 + e3;
#pragma unroll
    for (int off = 32; off > 0; off >>= 1)
        s += __shfl_xor(s, off);
    if (lane == 0) reds[wid] = s;
    __syncthreads();
    s = reds[0] + reds[1] + reds[2] + reds[3];

    const float inv = 1.0f / s;
    float4 o; o.x = e0 * inv; o.y = e1 * inv; o.z = e2 * inv; o.w = e3 * inv;
    *reinterpret_cast<float4*>(&p[t << 2]) = o;
}

// ---------------------------------------------------------------------------
// Transpose V: qkv[b*1024+m][2*768+h*64+d] (bf16) -> Vt[bh][d][m]
// ---------------------------------------------------------------------------
__global__ __launch_bounds__(256) void transpose_v(
    const short* __restrict__ qkv, short* __restrict__ Vt)
{
    __shared__ short T[64][72];
    const int bh = blockIdx.y, b = bh / HEADS_, h = bh % HEADS_;
    const int m0 = blockIdx.x * 64;
    const int t = threadIdx.x;
    const size_t vbase = (size_t)(b * N_) * QKVF + 2 * EMB_ + h * HDIM_;

#pragma unroll
    for (int p = 0; p < 2; ++p) {
        const int ci = p * 256 + t;          // 0..511
        const int r = ci >> 3, c = ci & 7;   // m-row, d-chunk
        const short8 v = *reinterpret_cast<const short8*>(
            &qkv[vbase + (size_t)(m0 + r) * QKVF + c * 8]);
#pragma unroll
        for (int j = 0; j < 8; ++j) T[c * 8 + j][r] = v[j];
    }
    __syncthreads();
#pragma unroll
    for (int p = 0; p < 2; ++p) {
        const int ci = p * 256 + t;
        const int d = ci >> 3, c = ci & 7;
        short8 v;
#pragma unroll
        for (int j = 0; j < 8; ++j) v[j] = T[d][c * 8 + j];
        *reinterpret_cast<short8*>(&Vt[((size_t)bh * 64 + d) * N_ + m0 + c * 8]) = v;
    }
}

// ---------------------------------------------------------------------------
// attn @ V: O[b*1024+n][h*64+d] (bf16) = sum_m P[bh,n,m] * Vt[bh,d,m]
// Block: 128 n-rows x 64 d-cols, BK=64 over m. P converted fp32->bf16 into
// padded LDS [128][72]; Vt staged via global_load_lds, swizzled.
// 4 waves, each 32 rows x 64 cols (2x4 tiles).
// ---------------------------------------------------------------------------
__global__ __launch_bounds__(256) void mfma_attnv(
    const float* __restrict__ attn, const short* __restrict__ Vt,
    short* __restrict__ O)
{
    __shared__ short Ps[128 * 72];
    __shared__ short Vs[64 * 64];

    const int t = threadIdx.x, lane = t & 63, w = t >> 6;
    const int bh = blockIdx.y, b = bh / HEADS_, h = bh % HEADS_;
    const int n0 = blockIdx.x * 128;
    const int m = lane & 15, kc = lane >> 4;

    floatx4 acc[2][4] = {};

    for (int k0 = 0; k0 < N_; k0 += 64) {
        __syncthreads();
        // stage P: thread t -> row r = t>>1, 32 cols at (t&1)*32
        {
            const int r = t >> 1, c0 = (t & 1) * 32;
            const float* src = &attn[((size_t)bh * N_ + n0 + r) * N_ + k0 + c0];
#pragma unroll
            for (int q = 0; q < 4; ++q) {
                const float4 u = *reinterpret_cast<const float4*>(&src[q * 8]);
                const float4 v = *reinterpret_cast<const float4*>(&src[q * 8 + 4]);
                short8 s;
                s[0] = f32_to_bf16(u.x); s[1] = f32_to_bf16(u.y);
                s[2] = f32_to_bf16(u.z); s[3] = f32_to_bf16(u.w);
                s[4] = f32_to_bf16(v.x); s[5] = f32_to_bf16(v.y);
                s[6] = f32_to_bf16(v.z); s[7] = f32_to_bf16(v.w);
                *reinterpret_cast<short8*>(&Ps[r * 72 + c0 + q * 8]) = s;
            }
        }
        // stage Vt tile: 64 d-rows x 64 m, swizzled
#pragma unroll
        for (int p = 0; p < 2; ++p) {
            const int ci = p * 256 + w * 64 + lane;
            const int r = ci >> 3, c = ci & 7;
            const int g = c ^ (r & 7);
            gload_lds16(&Vt[((size_t)bh * 64 + r) * N_ + k0 + g * 8],
                        &Vs[(p * 256 + w * 64) * 8]);
        }
        __syncthreads();

#pragma unroll
        for (int ks = 0; ks < 2; ++ks) {
            const int chunk = ks * 4 + kc;
            const int pcs = chunk ^ (m & 7);
            short8 af[2], bf[4];
#pragma unroll
            for (int i = 0; i < 2; ++i)
                af[i] = *reinterpret_cast<const short8*>(
                    &Ps[(w * 32 + i * 16 + m) * 72 + chunk * 8]);
#pragma unroll
            for (int j = 0; j < 4; ++j)
                bf[j] = *reinterpret_cast<const short8*>(
                    &Vs[((j * 16 + m) * 8 + pcs) * 8]);
#pragma unroll
            for (int i = 0; i < 2; ++i)
#pragma unroll
                for (int j = 0; j < 4; ++j)
                    acc[i][j] = mfma16(af[i], bf[j], acc[i][j]);
        }
    }

    const int rq = lane >> 4;
#pragma unroll
    for (int i = 0; i < 2; ++i)
#pragma unroll
        for (int j = 0; j < 4; ++j)
#pragma unroll
            for (int rg = 0; rg < 4; ++rg) {
                const int row = n0 + w * 32 + i * 16 + rq * 4 + rg;
                const int col = h * HDIM_ + j * 16 + m;
                O[(size_t)(b * N_ + row) * EMB_ + col] = f32_to_bf16(acc[i][j][rg]);
            }
}

// ---------------------------------------------------------------------------
extern "C" void kernel_launch(void* const* d_in, const int* in_sizes, int n_in,
                              void* d_out, int out_size, void* d_ws, size_t ws_size,
                              hipStream_t stream)
{
    const float* x     = (const float*)d_in[0];
    const float* w_qkv = (const float*)d_in[1];
    const float* b_qkv = (const float*)d_in[2];
    const float* w_out = (const float*)d_in[3];
    const float* b_out = (const float*)d_in[4];

    float* out  = (float*)d_out;
    float* attn = out + OUT_ELEMS;

    // workspace layout (bf16 shorts)
    short* qkvb = (short*)d_ws;                                   // 8192 x 2304
    short* xb   = qkvb + (size_t)M_TOK * QKVF;                    // 8192 x 768
    short* wqb  = xb   + OUT_ELEMS;                               // 2304 x 768
    short* wob  = wqb  + (size_t)QKVF * EMB_;                     // 768 x 768
    short* Vt   = wob  + (size_t)EMB_ * EMB_;                     // 96 x 64 x 1024
    short* O    = Vt   + (size_t)B_ * HEADS_ * HDIM_ * N_;        // 8192 x 768

    const dim3 blk(256);

    // casts
    cast_kernel<<<dim3(OUT_ELEMS / 1024), blk, 0, stream>>>(x, xb);
    cast_kernel<<<dim3((QKVF * EMB_) / 1024), blk, 0, stream>>>(w_qkv, wqb);
    cast_kernel<<<dim3((EMB_ * EMB_) / 1024), blk, 0, stream>>>(w_out, wob);

    // 1. QKV projection (bf16 out)
    mfma_gemm_bt<1><<<dim3(QKVF / 128, M_TOK / 128), blk, 0, stream>>>(
        xb, EMB_, wqb, EMB_, b_qkv, qkvb, QKVF, EMB_);

    // 2. V transpose
    transpose_v<<<dim3(N_ / 64, B_ * HEADS_), blk, 0, stream>>>(qkvb, Vt);

    // 3. scores -> attn region (fp32 scaled logits)
    mfma_scores<<<dim3(N_ / 128, N_ / 128, B_ * HEADS_), blk, 0, stream>>>(qkvb, attn);

    // 4. softmax in-place
    softmax_kernel<<<dim3(B_ * HEADS_ * N_), blk, 0, stream>>>(attn);

    // 5. attn @ V -> O (bf16)
    mfma_attnv<<<dim3(N_ / 128, B_ * HEADS_), blk, 0, stream>>>(attn, Vt, O);

    // 6. output projection (fp32 out + bias)
    mfma_gemm_bt<0><<<dim3(EMB_ / 128, M_TOK / 128), blk, 0, stream>>>(
        O, EMB_, wob, EMB_, b_out, out, EMB_, EMB_);
}